// Round 5
// baseline (10452.407 us; speedup 1.0000x reference)
//
#include <hip/hip_runtime.h>
#include <math.h>

namespace {

typedef __attribute__((ext_vector_type(8))) short s8b;   // 8 x bf16 (bit pattern)
typedef __attribute__((ext_vector_type(4))) float f4;
typedef unsigned long long u64;

constexpr int B_ = 128;
constexpr int T_ = 500;
constexpr int F_ = 64;
constexpr int U_ = 512;
constexpr int NCLS_ = 11;
constexpr int HU = B_ * U_;           // 65536
constexpr float R_ON_ = 0.05f;
constexpr float ALPHA_ = 0.001f;

constexpr int GRID_BLOCKS = 192;      // 64 cell0(+classifier) + 128 cell1
constexpr int NGRP = 24;              // barrier groups
constexpr int GSZ = 8;                // blocks per group (24*8 = 192)
constexpr int NPH = 502;              // phases 0..501

__device__ __forceinline__ ushort bf16_rne(float f) {
  union { float f; unsigned u; } v; v.f = f;
  unsigned r = (v.u + 0x7fffu + ((v.u >> 16) & 1u)) >> 16;
  return (ushort)r;
}
__device__ __forceinline__ float bf16_f(ushort h) {
  union { unsigned u; float f; } v; v.u = ((unsigned)h) << 16; return v.f;
}

__device__ __forceinline__ void st_u64(ushort* p, u64 v) {
  __hip_atomic_store((u64*)p, v, __ATOMIC_RELAXED, __HIP_MEMORY_SCOPE_AGENT);
}
__device__ __forceinline__ u64 ld_u64(const ushort* p) {
  return __hip_atomic_load((const u64*)p, __ATOMIC_RELAXED, __HIP_MEMORY_SCOPE_AGENT);
}
__device__ __forceinline__ u64 pack4(const ushort* h) {
  return (u64)h[0] | ((u64)h[1] << 16) | ((u64)h[2] << 32) | ((u64)h[3] << 48);
}

// LLC-coherent (L1/L2-bypass) 16B fragment load. ASYNC: result valid only
// after an s_waitcnt that covers it, + sched_barrier(0).
#define LDFRAG(dst, src) \
  asm volatile("global_load_dwordx4 %0, %1, off sc0 sc1" : "=&v"(dst) : "v"(src))

#define WAITN(N) do { \
  asm volatile("s_waitcnt vmcnt(" #N ")" ::: "memory"); \
  __builtin_amdgcn_sched_barrier(0); \
} while (0)

// fragment element offset (in ushorts) for state element (b, k)
__device__ __forceinline__ int foff(int b, int k) {
  return (((k >> 5) * 8 + (b >> 4)) * 64 + ((b & 15) | (((k >> 3) & 3) << 4))) * 8 + (k & 7);
}

// Fence-free hierarchical grid barrier over monotonic counters at LLC.
__device__ __forceinline__ void phase_barrier(unsigned* grp, unsigned* root,
                                              unsigned* gen, int gid, unsigned ph) {
  asm volatile("s_waitcnt vmcnt(0)" ::: "memory");   // per-wave store drain
  __syncthreads();
  if (threadIdx.x == 0) {
    const unsigned old =
        __hip_atomic_fetch_add(&grp[gid * 32], 1u, __ATOMIC_RELAXED, __HIP_MEMORY_SCOPE_AGENT);
    if (old == ph * GSZ + (GSZ - 1)) {
      const unsigned r =
          __hip_atomic_fetch_add(root, 1u, __ATOMIC_RELAXED, __HIP_MEMORY_SCOPE_AGENT);
      if (r == ph * NGRP + (NGRP - 1)) {
        __hip_atomic_store(gen, ph + 1u, __ATOMIC_RELAXED, __HIP_MEMORY_SCOPE_AGENT);
      }
    }
    unsigned it = 0;
    for (;;) {
      const unsigned cur = ((++it & 255u) == 0u)
          ? __hip_atomic_load(gen, __ATOMIC_ACQUIRE, __HIP_MEMORY_SCOPE_AGENT)
          : __hip_atomic_load(gen, __ATOMIC_RELAXED, __HIP_MEMORY_SCOPE_AGENT);
      if (cur >= ph + 1u) break;
      __builtin_amdgcn_s_sleep(2);
    }
  }
  __syncthreads();
}

// Persistent weight fragments (hi/lo bf16 split) from fp32 weights. One-time.
template <int NKS>
__device__ __forceinline__ void load_weights(
    s8b (&wh)[NKS], s8b (&wl)[NKS],
    const float* __restrict__ W1, int K1, const float* __restrict__ W2,
    int n, int kbase, int krow)
{
#pragma unroll
  for (int ks = 0; ks < NKS; ++ks) {
#pragma unroll
    for (int j = 0; j < 8; ++j) {
      const int kg = kbase + ks * 32 + krow + j;
      const float* src = (kg < K1) ? (W1 + (size_t)kg * 2048)
                                   : (W2 + (size_t)(kg - K1) * 2048);
      const float wv = src[n];
      const ushort hi = bf16_rne(wv);
      const ushort lo = bf16_rne(wv - bf16_f(hi));
      wh[ks][j] = (short)hi;
      wl[ks][j] = (short)lo;
    }
  }
}

// Unpipelined GEMM slice (cell0): 16 cols x 4 row-tiles x NKS*32 K.
template <int NKS>
__device__ __forceinline__ void gemm_c0(
    const s8b (&wh)[NKS], const s8b (&wl)[NKS],
    const ushort* __restrict__ Ahi, const ushort* __restrict__ Alo,
    int kbbase, bool withx, int t, const float* __restrict__ inputs,
    int lane, float* __restrict__ z_s, int zrow, int rtbase)
{
  const int rbase = (lane >> 4) * 4;
  const int krow = (lane >> 4) * 8;
#pragma unroll
  for (int r = 0; r < 4; ++r) {
    const int rt = rtbase + r;
    s8b sh[NKS], sl[NKS];
#pragma unroll
    for (int ks = 0; ks < NKS; ++ks) {
      if (withx && ks < 2) continue;
      const int e = (((kbbase + ks) * 8 + rt) * 64 + lane) * 8;
      LDFRAG(sh[ks], Ahi + e);
      LDFRAG(sl[ks], Alo + e);
    }
    if (withx) {
      const int row = rt * 16 + (lane & 15);
#pragma unroll
      for (int ks = 0; ks < 2; ++ks) {
        const float* xp = inputs + ((size_t)row * T_ + t) * F_ + ks * 32 + krow;
        const float4 v0 = *(const float4*)xp;
        const float4 v1 = *(const float4*)(xp + 4);
        const float xv[8] = {v0.x, v0.y, v0.z, v0.w, v1.x, v1.y, v1.z, v1.w};
#pragma unroll
        for (int j = 0; j < 8; ++j) {
          const ushort hi = bf16_rne(xv[j]);
          sh[ks][j] = (short)hi;
          sl[ks][j] = (short)bf16_rne(xv[j] - bf16_f(hi));
        }
      }
    }
    WAITN(0);
    f4 a0 = {0.f, 0.f, 0.f, 0.f};
    f4 a1 = {0.f, 0.f, 0.f, 0.f};
    f4 a2 = {0.f, 0.f, 0.f, 0.f};
#pragma unroll
    for (int ks = 0; ks < NKS; ++ks) {
      a0 = __builtin_amdgcn_mfma_f32_16x16x32_bf16(sh[ks], wh[ks], a0, 0, 0, 0);
      a1 = __builtin_amdgcn_mfma_f32_16x16x32_bf16(sl[ks], wh[ks], a1, 0, 0, 0);
      a2 = __builtin_amdgcn_mfma_f32_16x16x32_bf16(sh[ks], wl[ks], a2, 0, 0, 0);
    }
    const f4 red = a0 + a1 + a2;
#pragma unroll
    for (int j = 0; j < 4; ++j)
      atomicAdd(&z_s[zrow * 133 + rt * 16 + rbase + j], red[j]);
  }
}

// 8-K-step MFMA cluster for the pipelined cell1 path.
__device__ __forceinline__ void mm8(
    const s8b (&sh)[8], const s8b (&sl)[8],
    const s8b (&wh)[8], const s8b (&wl)[8], f4& out)
{
  f4 a0 = {0.f, 0.f, 0.f, 0.f};
  f4 a1 = {0.f, 0.f, 0.f, 0.f};
  f4 a2 = {0.f, 0.f, 0.f, 0.f};
#pragma unroll
  for (int ks = 0; ks < 8; ++ks) {
    a0 = __builtin_amdgcn_mfma_f32_16x16x32_bf16(sh[ks], wh[ks], a0, 0, 0, 0);
    a1 = __builtin_amdgcn_mfma_f32_16x16x32_bf16(sl[ks], wh[ks], a1, 0, 0, 0);
    a2 = __builtin_amdgcn_mfma_f32_16x16x32_bf16(sh[ks], wl[ks], a2, 0, 0, 0);
  }
  out = a0 + a1 + a2;
}

// Fused PhasedLSTM elementwise for NU units; c/h_old in registers.
template <int NU>
__device__ __forceinline__ void elem_update(
    const float* __restrict__ z_s, int b, int t, int u0,
    const float* __restrict__ bias, const float* __restrict__ tau,
    const float* __restrict__ shift, const float* __restrict__ timesT,
    float (&c8)[NU], float (&h8)[NU],
    ushort* __restrict__ hhi_w, ushort* __restrict__ hlo_w)
{
  const float tt = timesT[t * B_ + b];
  ushort vh[NU], vl[NU];
#pragma unroll
  for (int uu = 0; uu < NU; ++uu) {
    const int u = u0 + uu;
    const float zi = z_s[(4 * uu + 0) * 133 + b] + bias[u];
    const float zf = z_s[(4 * uu + 1) * 133 + b] + bias[512 + u];
    const float zg = z_s[(4 * uu + 2) * 133 + b] + bias[1024 + u];
    const float zo = z_s[(4 * uu + 3) * 133 + b] + bias[1536 + u];

    const float ig = 1.f / (1.f + expf(-zi));
    const float fg = 1.f / (1.f + expf(-zf));
    const float gg = tanhf(zg);
    const float og = 1.f / (1.f + expf(-zo));

    const float c_old = c8[uu];
    const float c_t = fg * c_old + ig * gg;
    const float h_t = og * tanhf(c_t);

    const float tau_u = tau[u];
    float phi = fmodf(tt - shift[u], tau_u);
    if (phi < 0.f) phi += tau_u;
    phi /= tau_u;
    float kt;
    if (phi < 0.5f * R_ON_)      kt = phi * (2.0f / R_ON_);
    else if (phi < R_ON_)        kt = 2.0f - phi * (2.0f / R_ON_);
    else                         kt = ALPHA_ * phi;

    const float cn = kt * c_t + (1.0f - kt) * c_old;
    const float hn = kt * h_t + (1.0f - kt) * h8[uu];
    c8[uu] = cn;
    h8[uu] = hn;
    const ushort hi = bf16_rne(hn);
    vh[uu] = hi;
    vl[uu] = bf16_rne(hn - bf16_f(hi));
  }
  const int base = foff(b, u0);
#pragma unroll
  for (int q = 0; q < NU / 4; ++q) {
    st_u64(hhi_w + base + 4 * q, pack4(&vh[4 * q]));
    st_u64(hlo_w + base + 4 * q, pack4(&vl[4 * q]));
  }
}

__global__ void init_kernel(unsigned* state_u32, const float* times, float* timesT,
                            unsigned* bar) {
  const int i = blockIdx.x * blockDim.x + threadIdx.x;
  if (i < 4 * HU) state_u32[i] = 0u;          // 8*HU ushorts
  if (i < T_ * B_) {
    const int t = i >> 7, b = i & 127;
    timesT[i] = times[b * T_ + t];
  }
  if (i < 4096) bar[i] = 0u;
}

// Phase ph: cell0 t=ph (blocks 0..63, 8 units, + classifier t=ph-2),
// cell1 t=ph-1 (blocks 64..191, 4 units). One grid barrier per phase.
__global__ __launch_bounds__(512, 2) void plstm_kernel(
    const float* __restrict__ inputs,
    const float* __restrict__ k0, const float* __restrict__ rk0,
    const float* __restrict__ b0, const float* __restrict__ tau0, const float* __restrict__ s0,
    const float* __restrict__ k1, const float* __restrict__ rk1,
    const float* __restrict__ b1, const float* __restrict__ tau1, const float* __restrict__ s1,
    const float* __restrict__ wfc, const float* __restrict__ bfc,
    float* __restrict__ out,
    ushort* __restrict__ h0hi, ushort* __restrict__ h0lo,
    ushort* __restrict__ h1hi, ushort* __restrict__ h1lo,
    const float* __restrict__ timesT,
    unsigned* __restrict__ bar)
{
  __shared__ __align__(16) float z_s[32 * 133];
  __shared__ float cls_s[4][12];

  const int bid = blockIdx.x;
  const int tid = threadIdx.x;
  const int w = tid >> 6;
  const int lane = tid & 63;
  const int krow = (lane >> 4) * 8;
  const int gid = bid >> 3;
  unsigned* grp = bar;
  unsigned* root = bar + NGRP * 32;
  unsigned* gen = bar + NGRP * 32 + 32;

  if (bid < 64) {
    // ---- cell 0 (+ classifier): 8 units; waves = ct(2) x ksl(2) x rh(2) ----
    const int u0 = bid * 8;
    const int ct = w & 1;
    const int ksl = (w >> 1) & 1;
    const int rh = w >> 2;
    const int c_loc = ct * 16 + (lane & 15);
    const int n = (c_loc & 3) * 512 + u0 + (c_loc >> 2);
    s8b wh[9], wl[9];
    load_weights<9>(wh, wl, k0, 64, rk0, n, ksl * 288, krow);
    float c8[8], h8[8];
#pragma unroll
    for (int i = 0; i < 8; ++i) { c8[i] = 0.f; h8[i] = 0.f; }

    for (unsigned ph = 0; ph < NPH; ++ph) {
      const bool work = ph < T_;
      const bool clsw = ph >= 2;
      if (work) {
        for (int i = tid; i < 32 * 133; i += 512) z_s[i] = 0.f;
      }
      if (clsw && w < 4) {  // classifier partial for t = ph-2
        const int r = w >> 1;
        const int bcls = 2 * bid + r;
        const int idx = ((w & 1) << 6) | lane;   // 0..127
        const int u = idx * 4;
        const size_t pcl = (size_t)((ph + 1) & 1) * HU;
        const int e = foff(bcls, u);
        const u64 hu = ld_u64(h1hi + pcl + e);
        const u64 lu = ld_u64(h1lo + pcl + e);
        float acc[NCLS_];
#pragma unroll
        for (int c = 0; c < NCLS_; ++c) acc[c] = 0.f;
#pragma unroll
        for (int j = 0; j < 4; ++j) {
          const float h = bf16_f((ushort)(hu >> (16 * j))) + bf16_f((ushort)(lu >> (16 * j)));
          const float* wr = wfc + (size_t)(u + j) * NCLS_;
#pragma unroll
          for (int c = 0; c < NCLS_; ++c) acc[c] = fmaf(h, wr[c], acc[c]);
        }
#pragma unroll
        for (int off = 32; off >= 1; off >>= 1) {
#pragma unroll
          for (int c = 0; c < NCLS_; ++c) acc[c] += __shfl_xor(acc[c], off, 64);
        }
        if (lane == 0) {
#pragma unroll
          for (int c = 0; c < NCLS_; ++c) cls_s[w][c] = acc[c];
        }
      }
      __syncthreads();
      if (work) {
        const size_t rp = (size_t)(ph & 1) * HU;
        gemm_c0<9>(wh, wl, h0hi + rp, h0lo + rp, ksl ? 7 : -2,
                   ksl == 0, (int)ph, inputs, lane, z_s, c_loc, rh * 4);
      }
      __syncthreads();
      if (work && tid < 128) {
        const size_t wp = (size_t)((ph + 1) & 1) * HU;
        elem_update<8>(z_s, tid, (int)ph, u0, b0, tau0, s0, timesT,
                       c8, h8, h0hi + wp, h0lo + wp);
      }
      if (clsw && tid < 2) {
        const int t_cl = (int)ph - 2;
        const int bcls = 2 * bid + tid;
        float lg[NCLS_];
        float m = -1e30f;
#pragma unroll
        for (int c = 0; c < NCLS_; ++c) {
          lg[c] = cls_s[2 * tid][c] + cls_s[2 * tid + 1][c] + bfc[c];
          m = fmaxf(m, lg[c]);
        }
        float s = 0.f;
#pragma unroll
        for (int c = 0; c < NCLS_; ++c) { lg[c] = expf(lg[c] - m); s += lg[c]; }
        const float inv = 1.0f / s;
        float* op = out + ((size_t)bcls * T_ + t_cl) * NCLS_;
#pragma unroll
        for (int c = 0; c < NCLS_; ++c) op[c] = lg[c] * inv;
      }
      if (ph < NPH - 1) phase_barrier(grp, root, gen, gid, ph);
    }
  } else {
    // ---- cell 1: 4 units; waves = ksl(4, 256 K each) x rh(2, 4 rt each) ----
    const int cb = bid - 64;                 // 0..127
    const int u0 = cb * 4;
    const int ksl = w & 3;
    const int rh = w >> 2;
    const int c_loc = lane & 15;
    const int rbase = (lane >> 4) * 4;
    const int n = (c_loc & 3) * 512 + u0 + (c_loc >> 2);
    s8b wh[8], wl[8];
    load_weights<8>(wh, wl, k1, 512, rk1, n, ksl * 256, krow);
    float c4[4], h4[4];
#pragma unroll
    for (int i = 0; i < 4; ++i) { c4[i] = 0.f; h4[i] = 0.f; }

    for (unsigned ph = 0; ph < NPH; ++ph) {
      const int t = (int)ph - 1;
      const bool work = (t >= 0 && t < T_);
      if (work) {
        for (int i = tid; i < 16 * 133; i += 512) z_s[i] = 0.f;
      }
      __syncthreads();
      if (work) {
        const ushort* Ahi;
        const ushort* Alo;
        int kbb;
        if (ksl < 2) {             // k 0..511: h0(t), parity ph&1
          const size_t p = (size_t)(ph & 1) * HU;
          Ahi = h0hi + p; Alo = h0lo + p; kbb = ksl * 8;
        } else {                   // k 512..1023: h1(t-1), parity (ph+1)&1
          const size_t p = (size_t)((ph + 1) & 1) * HU;
          Ahi = h1hi + p; Alo = h1lo + p; kbb = (ksl - 2) * 8;
        }
        const int r0 = rh * 4;

        s8b shA[8], slA[8], shB[8], slB[8];
        f4 red;

#define ISSUE8(SH, SL, RT) do { \
  _Pragma("unroll") \
  for (int ks_ = 0; ks_ < 8; ++ks_) { \
    const int e_ = (((kbb + ks_) * 8 + (RT)) * 64 + lane) * 8; \
    LDFRAG(SH[ks_], Ahi + e_); \
    LDFRAG(SL[ks_], Alo + e_); \
  } \
} while (0)
#define ZADD(V, RT) do { \
  _Pragma("unroll") \
  for (int j_ = 0; j_ < 4; ++j_) \
    atomicAdd(&z_s[c_loc * 133 + (RT) * 16 + rbase + j_], (V)[j_]); \
} while (0)

        ISSUE8(shA, slA, r0);
        ISSUE8(shB, slB, r0 + 1);
        WAITN(16);
        mm8(shA, slA, wh, wl, red); ZADD(red, r0);
        ISSUE8(shA, slA, r0 + 2);
        WAITN(16);
        mm8(shB, slB, wh, wl, red); ZADD(red, r0 + 1);
        ISSUE8(shB, slB, r0 + 3);
        WAITN(16);
        mm8(shA, slA, wh, wl, red); ZADD(red, r0 + 2);
        WAITN(0);
        mm8(shB, slB, wh, wl, red); ZADD(red, r0 + 3);
#undef ISSUE8
#undef ZADD
      }
      __syncthreads();
      if (work && tid < 128) {
        const size_t wp = (size_t)(ph & 1) * HU;
        elem_update<4>(z_s, tid, t, u0, b1, tau1, s1, timesT,
                       c4, h4, h1hi + wp, h1lo + wp);
      }
      if (ph < NPH - 1) phase_barrier(grp, root, gen, gid, ph);
    }
  }
}

}  // namespace

extern "C" void kernel_launch(void* const* d_in, const int* in_sizes, int n_in,
                              void* d_out, int out_size, void* d_ws, size_t ws_size,
                              hipStream_t stream) {
  const float* inputs = (const float*)d_in[0];
  const float* times  = (const float*)d_in[1];
  const float* k0     = (const float*)d_in[2];
  const float* rk0    = (const float*)d_in[3];
  const float* b0     = (const float*)d_in[4];
  const float* tau0   = (const float*)d_in[5];
  const float* s0     = (const float*)d_in[6];
  const float* k1     = (const float*)d_in[7];
  const float* rk1    = (const float*)d_in[8];
  const float* b1     = (const float*)d_in[9];
  const float* tau1   = (const float*)d_in[10];
  const float* s1     = (const float*)d_in[11];
  const float* wfc    = (const float*)d_in[12];
  const float* bfc    = (const float*)d_in[13];
  float* out = (float*)d_out;

  ushort* h0hi = (ushort*)d_ws;            // [2][HU]
  ushort* h0lo = h0hi + 2 * HU;
  ushort* h1hi = h0lo + 2 * HU;
  ushort* h1lo = h1hi + 2 * HU;
  float* timesT = (float*)(h1lo + 2 * HU); // [T][B]
  unsigned* bar = (unsigned*)(timesT + T_ * B_);

  hipLaunchKernelGGL(init_kernel, dim3(1024), dim3(256), 0, stream,
                     (unsigned*)d_ws, times, timesT, bar);
  hipLaunchKernelGGL(plstm_kernel, dim3(GRID_BLOCKS), dim3(512), 0, stream,
                     inputs, k0, rk0, b0, tau0, s0,
                     k1, rk1, b1, tau1, s1, wfc, bfc, out,
                     h0hi, h0lo, h1hi, h1lo, timesT, bar);
}